// Round 1
// baseline (43.146 us; speedup 1.0000x reference)
//
#include <hip/hip_runtime.h>
#include <hip/hip_bf16.h>

// RGCN fused: out = relu( [x | agg_r0..agg_r15] @ [w_self | w_rel]^T )
// B=4096, S=10, R=16, F=128, K_total=2176.
// 128 blocks x 512 threads (8 waves), BT=32 target nodes per block.

#define BT   32
#define LDA  2184            // A row length in bf16 elems (2176 + 8 pad -> 2-way-max LDS banking)
#define NTHR 512

typedef __attribute__((ext_vector_type(8))) short short8;   // 8 bf16 (4 VGPRs)
typedef __attribute__((ext_vector_type(4))) float f32x4;    // MFMA accumulator

// pack two fp32 -> two bf16 (truncation) in one v_perm_b32
__device__ __forceinline__ unsigned int pk2_trunc(float lo, float hi) {
  return __builtin_amdgcn_perm(__float_as_uint(hi), __float_as_uint(lo), 0x07060302u);
}
// round-to-nearest-even fp32 -> bf16 bits
__device__ __forceinline__ unsigned int bfrne(float f) {
  unsigned int u = __float_as_uint(f);
  return (u + 0x7fffu + ((u >> 16) & 1u)) >> 16;
}
__device__ __forceinline__ unsigned int pk2_rne(float lo, float hi) {
  return bfrne(lo) | (bfrne(hi) << 16);
}

__global__ __launch_bounds__(NTHR, 2)
void rgcn_fused(const float* __restrict__ emb,
                const float* __restrict__ w_self,
                const float* __restrict__ w_rel,
                const int*   __restrict__ nodes,
                const int*   __restrict__ neighbors,
                const int*   __restrict__ rel_mask,
                float*       __restrict__ out)
{
  __shared__ alignas(16) unsigned short A_t[BT * LDA];   // 139,776 B (bf16 bits)
  __shared__ alignas(16) float mscale[BT][10][16];       //  20,480 B

  const int t  = threadIdx.x;
  const int b0 = blockIdx.x * BT;

  // ---------- Phase A0: rel_mask -> mscale[b][s][r] = m/(count+eps) ----------
  {
    const int bi = t >> 4, r = t & 15;                  // 512 threads = 32x16 (bi,r) pairs
    const int* mp = rel_mask + (b0 + bi) * 160 + r;
    int mb[10]; int c = 0;
    #pragma unroll
    for (int s = 0; s < 10; ++s) { mb[s] = mp[s * 16]; c += mb[s]; }
    const float inv = 1.0f / ((float)c + 1e-10f);
    #pragma unroll
    for (int s = 0; s < 10; ++s) mscale[bi][s][r] = mb[s] ? inv : 0.0f;
  }
  __syncthreads();

  const int w = t >> 6;       // wave 0..7
  const int l = t & 63;       // lane

  // ---------- Phase A: build A_t rows (self emb + 16 masked means), bf16 ----------
  {
    const int half = l >> 5;            // lanes 0-31: bi_lo, 32-63: bi_hi
    const int f0   = (l & 31) * 4;      // 4 features per lane (float4 coalesced)
    #pragma unroll
    for (int pair = 0; pair < 2; ++pair) {
      const int bi = w * 4 + pair * 2 + half;
      const int b  = b0 + bi;
      int nb[10];
      #pragma unroll
      for (int s = 0; s < 10; ++s) nb[s] = neighbors[b * 10 + s];
      const int node = nodes[b];
      const float4 x4 = *(const float4*)(emb + (size_t)node * 128 + f0);
      char* arow = (char*)A_t + bi * (LDA * 2);
      uint2 sv; sv.x = pk2_rne(x4.x, x4.y); sv.y = pk2_rne(x4.z, x4.w);
      *(uint2*)(arow + f0 * 2) = sv;                       // self block, k in [0,128)

      float acc[16][4];
      #pragma unroll
      for (int r = 0; r < 16; ++r) { acc[r][0]=0.f; acc[r][1]=0.f; acc[r][2]=0.f; acc[r][3]=0.f; }

      #pragma unroll
      for (int sb = 0; sb < 2; ++sb) {                     // 2 batches of 5 gathers
        float4 nef[5];
        #pragma unroll
        for (int q = 0; q < 5; ++q)
          nef[q] = *(const float4*)(emb + (size_t)nb[sb * 5 + q] * 128 + f0);
        #pragma unroll
        for (int q = 0; q < 5; ++q) {
          const int s = sb * 5 + q;
          const float* msp = &mscale[bi][s][0];
          const float4 m0 = *(const float4*)(msp);
          const float4 m1 = *(const float4*)(msp + 4);
          const float4 m2 = *(const float4*)(msp + 8);
          const float4 m3 = *(const float4*)(msp + 12);
          const float ms[16] = {m0.x,m0.y,m0.z,m0.w, m1.x,m1.y,m1.z,m1.w,
                                m2.x,m2.y,m2.z,m2.w, m3.x,m3.y,m3.z,m3.w};
          const float4 ne = nef[q];
          #pragma unroll
          for (int r = 0; r < 16; ++r) {
            acc[r][0] += ms[r] * ne.x;
            acc[r][1] += ms[r] * ne.y;
            acc[r][2] += ms[r] * ne.z;
            acc[r][3] += ms[r] * ne.w;
          }
        }
      }
      #pragma unroll
      for (int r = 0; r < 16; ++r) {                       // agg_r block, k in [128+128r, 256+128r)
        uint2 wv; wv.x = pk2_rne(acc[r][0], acc[r][1]); wv.y = pk2_rne(acc[r][2], acc[r][3]);
        *(uint2*)(arow + (256 + r * 256) + f0 * 2) = wv;
      }
    }
  }
  __syncthreads();

  // ---------- Phase B: out = relu(A @ W^T) via mfma_f32_16x16x32_bf16 ----------
  {
    const int o0 = w * 16;                 // wave owns one 16-wide output-col tile
    const int lj = l >> 4, ln = l & 15;
    f32x4 acc0 = {0.f,0.f,0.f,0.f};        // b-rows 0..15
    f32x4 acc1 = {0.f,0.f,0.f,0.f};        // b-rows 16..31
    const char* arow0 = (const char*)A_t + ln * (LDA * 2);
    const char* arow1 = (const char*)A_t + (16 + ln) * (LDA * 2);
    #pragma unroll 4
    for (int ks = 0; ks < 68; ++ks) {
      const int kk = ks * 32 + lj * 8;
      // A fragments: lane holds A[row=ln][kk..kk+8) -> one ds_read_b128 each
      const short8 a0 = *(const short8*)(arow0 + kk * 2);
      const short8 a1 = *(const short8*)(arow1 + kk * 2);
      // B fragment: W[o0+ln][kk..kk+8) fp32 -> bf16 (trunc)
      const float* wp;
      if (ks < 4) wp = w_self + (o0 + ln) * 128 + kk;
      else        wp = w_rel + (((ks >> 2) - 1) * 128 + o0 + ln) * 128 + ((ks & 3) * 32 + lj * 8);
      const float4 wa = *(const float4*)wp;
      const float4 wb = *(const float4*)(wp + 4);
      union { unsigned int u[4]; short8 s; } cv;
      cv.u[0] = pk2_trunc(wa.x, wa.y);
      cv.u[1] = pk2_trunc(wa.z, wa.w);
      cv.u[2] = pk2_trunc(wb.x, wb.y);
      cv.u[3] = pk2_trunc(wb.z, wb.w);
      acc0 = __builtin_amdgcn_mfma_f32_16x16x32_bf16(a0, cv.s, acc0, 0, 0, 0);
      acc1 = __builtin_amdgcn_mfma_f32_16x16x32_bf16(a1, cv.s, acc1, 0, 0, 0);
    }
    // C/D layout (m89): col = lane&15, row = (lane>>4)*4 + j
    const int orow = o0 + ln;
    #pragma unroll
    for (int j = 0; j < 4; ++j) {
      const int bi0 = lj * 4 + j;
      out[(size_t)(b0 + bi0)      * 128 + orow] = fmaxf(acc0[j], 0.0f);
      out[(size_t)(b0 + 16 + bi0) * 128 + orow] = fmaxf(acc1[j], 0.0f);
    }
  }
}

extern "C" void kernel_launch(void* const* d_in, const int* in_sizes, int n_in,
                              void* d_out, int out_size, void* d_ws, size_t ws_size,
                              hipStream_t stream) {
  const float* emb       = (const float*)d_in[0];
  const float* w_self    = (const float*)d_in[1];
  const float* w_rel     = (const float*)d_in[2];
  const int*   nodes     = (const int*)d_in[3];
  const int*   neighbors = (const int*)d_in[4];
  const int*   rel_mask  = (const int*)d_in[5];
  float* out = (float*)d_out;
  (void)in_sizes; (void)n_in; (void)d_ws; (void)ws_size; (void)out_size;
  rgcn_fused<<<4096 / BT, NTHR, 0, stream>>>(emb, w_self, w_rel, nodes, neighbors, rel_mask, out);
}

// Round 2
// 25.753 us; speedup vs baseline: 1.6753x; 1.6753x over previous
//
#include <hip/hip_runtime.h>
#include <hip/hip_bf16.h>

// RGCN fused: out = relu( [x | agg_r0..agg_r15] @ [w_self | w_rel]^T )
// B=4096, S=10, R=16, F=128, K_total=2176.
// v2: BT=16 -> 256 blocks (all CUs). K-split phase B (A_t read 1x) + LDS
// partial reduction. W pre-packed to bf16 MFMA-fragment order in d_ws.

#define BT      16
#define LDA     2184           // bf16 elems per A_t row (2176 + 8 pad)
#define NTHR    512
#define K_STEPS 68             // 2176 / 32
#define W2_UNITS (K_STEPS * 8) // 544 (ks, otile) units
#define W2_BYTES (W2_UNITS * 64 * 16)  // 557,056

typedef __attribute__((ext_vector_type(8))) short short8;  // 8 bf16
typedef __attribute__((ext_vector_type(4))) float f32x4;   // MFMA acc

// fp32 pair -> packed bf16 (RNE) in one instruction
__device__ __forceinline__ unsigned int pk2_rne(float lo, float hi) {
  unsigned int r;
  asm("v_cvt_pk_bf16_f32 %0, %1, %2" : "=v"(r) : "v"(lo), "v"(hi));
  return r;
}

// ---- prep: W (fp32) -> bf16 fragments, layout [ks][ot][lane] 16B per lane ----
__global__ __launch_bounds__(256)
void wprep(const float* __restrict__ w_self, const float* __restrict__ w_rel,
           uint4* __restrict__ w2)
{
  const int u  = blockIdx.x * 4 + (threadIdx.x >> 6);   // 0..543
  const int l  = threadIdx.x & 63;
  const int ln = l & 15, lj = l >> 4;
  const int ks = u >> 3, ot = u & 7;
  const int o  = ot * 16 + ln;
  const int k0 = ks * 32 + lj * 8;
  const float* src;
  if (k0 < 128) src = w_self + o * 128 + k0;
  else {
    const int r = (k0 - 128) >> 7, kc = (k0 - 128) & 127;
    src = w_rel + ((size_t)(r * 128 + o)) * 128 + kc;
  }
  const float4 a = *(const float4*)src;
  const float4 b = *(const float4*)(src + 4);
  uint4 v;
  v.x = pk2_rne(a.x, a.y); v.y = pk2_rne(a.z, a.w);
  v.z = pk2_rne(b.x, b.y); v.w = pk2_rne(b.z, b.w);
  w2[u * 64 + l] = v;
}

template<bool USE_W2>
__global__ __launch_bounds__(NTHR, 2)
void rgcn_fused(const float* __restrict__ emb,
                const float* __restrict__ w_self,
                const float* __restrict__ w_rel,
                const int*   __restrict__ nodes,
                const int*   __restrict__ neighbors,
                const int*   __restrict__ rel_mask,
                const uint4* __restrict__ w2,
                float*       __restrict__ out)
{
  __shared__ alignas(16) char smem[80128];
  unsigned short* A_t = (unsigned short*)smem;                  // [16][2184] bf16
  float (*mscale)[10][16] = (float (*)[10][16])(smem + 69888);  // [16][10][16]

  const int t  = threadIdx.x;
  const int b0 = blockIdx.x * BT;
  const int l  = t & 63;
  const int w  = t >> 6;

  // ---------- A0: rel_mask -> mscale[b][s][r] = m/(count+eps) ----------
  if (t < 256) {
    const int bi = t >> 4, r = t & 15;
    const int* mp = rel_mask + (size_t)(b0 + bi) * 160 + r;
    int mb[10]; int c = 0;
    #pragma unroll
    for (int s = 0; s < 10; ++s) { mb[s] = mp[s * 16]; c += mb[s]; }
    const float inv = 1.0f / ((float)c + 1e-10f);
    #pragma unroll
    for (int s = 0; s < 10; ++s) mscale[bi][s][r] = mb[s] ? inv : 0.0f;
  }
  __syncthreads();

  // ---------- A: build A_t rows (self + 16 masked means), bf16 ----------
  {
    const int bi = t >> 5;          // node slot 0..15
    const int f0 = (t & 31) * 4;    // 4 features per lane
    const int b  = b0 + bi;
    const int node = nodes[b];
    int nb[10];
    #pragma unroll
    for (int s = 0; s < 10; ++s) nb[s] = neighbors[b * 10 + s];
    float4 ne[10];
    #pragma unroll
    for (int s = 0; s < 10; ++s)
      ne[s] = *(const float4*)(emb + (size_t)nb[s] * 128 + f0);
    const float4 x4 = *(const float4*)(emb + (size_t)node * 128 + f0);
    char* arow = (char*)A_t + bi * (LDA * 2);
    uint2 sv; sv.x = pk2_rne(x4.x, x4.y); sv.y = pk2_rne(x4.z, x4.w);
    *(uint2*)(arow + f0 * 2) = sv;                      // self block, k in [0,128)

    #pragma unroll
    for (int rc = 0; rc < 4; ++rc) {                    // 4 relations at a time
      float acc[4][4];
      #pragma unroll
      for (int rr = 0; rr < 4; ++rr) { acc[rr][0]=0.f; acc[rr][1]=0.f; acc[rr][2]=0.f; acc[rr][3]=0.f; }
      #pragma unroll
      for (int s = 0; s < 10; ++s) {
        const float4 ms = *(const float4*)(&mscale[bi][s][rc * 4]);
        const float m[4] = {ms.x, ms.y, ms.z, ms.w};
        const float4 v = ne[s];
        #pragma unroll
        for (int rr = 0; rr < 4; ++rr) {
          acc[rr][0] += m[rr] * v.x;
          acc[rr][1] += m[rr] * v.y;
          acc[rr][2] += m[rr] * v.z;
          acc[rr][3] += m[rr] * v.w;
        }
      }
      #pragma unroll
      for (int rr = 0; rr < 4; ++rr) {
        const int r = rc * 4 + rr;                      // k in [128+128r, 256+128r)
        uint2 v2; v2.x = pk2_rne(acc[rr][0], acc[rr][1]); v2.y = pk2_rne(acc[rr][2], acc[rr][3]);
        *(uint2*)(arow + 256 + r * 256 + f0 * 2) = v2;
      }
    }
  }
  __syncthreads();

  // ---------- B: K-split GEMM. wave w owns k-steps [ksb,kse), all 128 cols ----------
  const int ln = l & 15, lj = l >> 4;
  f32x4 acc[8];
  #pragma unroll
  for (int ot = 0; ot < 8; ++ot) acc[ot] = (f32x4){0.f, 0.f, 0.f, 0.f};
  {
    const int ksb = (w < 4) ? w * 9 : 36 + (w - 4) * 8;
    const int kse = ksb + ((w < 4) ? 9 : 8);
    const char* arow = (const char*)A_t + ln * (LDA * 2);
    for (int ks = ksb; ks < kse; ++ks) {
      const short8 a = *(const short8*)(arow + ks * 64 + lj * 16);
      #pragma unroll
      for (int ot = 0; ot < 8; ++ot) {
        short8 bf;
        if constexpr (USE_W2) {
          union { uint4 u; short8 s; } wv;
          wv.u = w2[(ks * 8 + ot) * 64 + l];
          bf = wv.s;
        } else {
          const int o  = ot * 16 + ln;
          const int k0 = ks * 32 + lj * 8;
          const float* wp;
          if (k0 < 128) wp = w_self + o * 128 + k0;
          else {
            const int r = (k0 - 128) >> 7, kc = (k0 - 128) & 127;
            wp = w_rel + ((size_t)(r * 128 + o)) * 128 + kc;
          }
          const float4 wa = *(const float4*)wp;
          const float4 wb = *(const float4*)(wp + 4);
          union { unsigned int u[4]; short8 s; } cv;
          cv.u[0] = pk2_rne(wa.x, wa.y);
          cv.u[1] = pk2_rne(wa.z, wa.w);
          cv.u[2] = pk2_rne(wb.x, wb.y);
          cv.u[3] = pk2_rne(wb.z, wb.w);
          bf = cv.s;
        }
        acc[ot] = __builtin_amdgcn_mfma_f32_16x16x32_bf16(a, bf, acc[ot], 0, 0, 0);
      }
    }
  }
  __syncthreads();

  // ---------- C: write per-k-group partials (aliases A_t region) ----------
  {
    float* P = (float*)smem;                            // [8][16][132] f32
    #pragma unroll
    for (int ot = 0; ot < 8; ++ot) {
      const int o = ot * 16 + ln;
      #pragma unroll
      for (int j = 0; j < 4; ++j)                       // row = lj*4+j (node), col = o
        P[(w * 16 + lj * 4 + j) * 132 + o] = acc[ot][j];
    }
  }
  __syncthreads();

  // ---------- D: 8-way reduce + relu + store ----------
  {
    const float* P = (const float*)smem;
    const int row = t >> 5, o0 = (t & 31) * 4;
    f32x4 s = {0.f, 0.f, 0.f, 0.f};
    #pragma unroll
    for (int g = 0; g < 8; ++g)
      s += *(const f32x4*)(P + (g * 16 + row) * 132 + o0);
    float4 o4;
    o4.x = fmaxf(s[0], 0.f); o4.y = fmaxf(s[1], 0.f);
    o4.z = fmaxf(s[2], 0.f); o4.w = fmaxf(s[3], 0.f);
    *(float4*)(out + (size_t)(b0 + row) * 128 + o0) = o4;
  }
}

extern "C" void kernel_launch(void* const* d_in, const int* in_sizes, int n_in,
                              void* d_out, int out_size, void* d_ws, size_t ws_size,
                              hipStream_t stream) {
  const float* emb       = (const float*)d_in[0];
  const float* w_self    = (const float*)d_in[1];
  const float* w_rel     = (const float*)d_in[2];
  const int*   nodes     = (const int*)d_in[3];
  const int*   neighbors = (const int*)d_in[4];
  const int*   rel_mask  = (const int*)d_in[5];
  float* out = (float*)d_out;
  (void)in_sizes; (void)n_in; (void)out_size;

  if (d_ws != nullptr && ws_size >= (size_t)W2_BYTES) {
    wprep<<<136, 256, 0, stream>>>(w_self, w_rel, (uint4*)d_ws);
    rgcn_fused<true><<<4096 / BT, NTHR, 0, stream>>>(
        emb, w_self, w_rel, nodes, neighbors, rel_mask, (const uint4*)d_ws, out);
  } else {
    rgcn_fused<false><<<4096 / BT, NTHR, 0, stream>>>(
        emb, w_self, w_rel, nodes, neighbors, rel_mask, nullptr, out);
  }
}